// Round 1
// baseline (1416.159 us; speedup 1.0000x reference)
//
#include <hip/hip_runtime.h>

// Problem constants (match reference)
constexpr int NODES = 100000;
constexpr int EDGES = 800000;
constexpr int DIM = 128;       // node dim
constexpr int EDIM = 8;        // edge attr dim
constexpr int HEADS = 8;

// ---------------------------------------------------------------------------
// Kernel A0: transpose W_node (128x128) into workspace: Wt[k][d] = W[d][k]
// ---------------------------------------------------------------------------
__global__ __launch_bounds__(256) void transpose_w(const float* __restrict__ W,
                                                   float* __restrict__ Wt) {
    int idx = blockIdx.x * 256 + threadIdx.x;   // 64 blocks * 256 = 16384
    int d = idx & 127;
    int k = idx >> 7;
    Wt[k * DIM + d] = W[d * DIM + k];
}

__device__ inline void fma4(float4& a, float s, const float4& w) {
    a.x += s * w.x; a.y += s * w.y; a.z += s * w.z; a.w += s * w.w;
}

// ---------------------------------------------------------------------------
// Kernel A: x_proj = x @ W.T + b   (reads pre-transposed Wt)
// 32 rows per block; 256 threads = 8 half-waves; half-wave h owns rows h*4..+3
// lane's dq (tid&31) owns output cols dq*4..dq*4+3.
// Wt staged in two 32KB halves (static LDS <= 64KB), x tile 16KB.
// ---------------------------------------------------------------------------
__global__ __launch_bounds__(256) void node_proj(const float* __restrict__ x,
                                                 const float* __restrict__ Wt,
                                                 const float* __restrict__ bn,
                                                 float* __restrict__ xp) {
    __shared__ float sWt[64 * DIM];   // 32KB: half of Wt (64 k-rows)
    __shared__ float sx[32 * DIM];    // 16KB: 32 node rows

    const int tid = threadIdx.x;
    const int row0 = blockIdx.x * 32;

    // stage x tile (float4, coalesced)
    {
        const float4* x4 = reinterpret_cast<const float4*>(x + (size_t)row0 * DIM);
        float4* sx4 = reinterpret_cast<float4*>(sx);
        #pragma unroll
        for (int i = tid; i < 32 * 32; i += 256) sx4[i] = x4[i];
    }

    const int hw = tid >> 5;    // half-wave 0..7
    const int dq = tid & 31;    // d-quad
    const int r0 = hw * 4;

    float4 a0 = {0,0,0,0}, a1 = {0,0,0,0}, a2 = {0,0,0,0}, a3 = {0,0,0,0};

    const float4* Wt4 = reinterpret_cast<const float4*>(Wt);
    float4* sWt4 = reinterpret_cast<float4*>(sWt);

    #pragma unroll
    for (int half = 0; half < 2; ++half) {
        __syncthreads();   // protect prior-iteration reads (and x staging on first pass)
        #pragma unroll
        for (int i = tid; i < 64 * 32; i += 256) sWt4[i] = Wt4[half * 2048 + i];
        __syncthreads();

        const int kbase = half * 64;
        #pragma unroll 4
        for (int k = 0; k < 64; ++k) {
            float4 w = *reinterpret_cast<const float4*>(&sWt[k * DIM + dq * 4]);
            float x0 = sx[(r0 + 0) * DIM + kbase + k];
            float x1 = sx[(r0 + 1) * DIM + kbase + k];
            float x2 = sx[(r0 + 2) * DIM + kbase + k];
            float x3 = sx[(r0 + 3) * DIM + kbase + k];
            fma4(a0, x0, w);
            fma4(a1, x1, w);
            fma4(a2, x2, w);
            fma4(a3, x3, w);
        }
    }

    float4 b = *reinterpret_cast<const float4*>(bn + dq * 4);
    a0.x += b.x; a0.y += b.y; a0.z += b.z; a0.w += b.w;
    a1.x += b.x; a1.y += b.y; a1.z += b.z; a1.w += b.w;
    a2.x += b.x; a2.y += b.y; a2.z += b.z; a2.w += b.w;
    a3.x += b.x; a3.y += b.y; a3.z += b.z; a3.w += b.w;

    float4* out4 = reinterpret_cast<float4*>(xp);
    out4[(size_t)(row0 + r0 + 0) * 32 + dq] = a0;
    out4[(size_t)(row0 + r0 + 1) * 32 + dq] = a1;
    out4[(size_t)(row0 + r0 + 2) * 32 + dq] = a2;
    out4[(size_t)(row0 + r0 + 3) * 32 + dq] = a3;
}

// ---------------------------------------------------------------------------
// Kernel B: per-edge gather + gate + scatter-add.
// 32 lanes per edge; lane l owns elements l*4..l*4+3 (head h = l>>2).
// Gate computed redundantly per lane (8 FMA + sigmoid).
// ---------------------------------------------------------------------------
__global__ __launch_bounds__(256) void edge_scatter(const int* __restrict__ ei,
                                                    const float* __restrict__ ea,
                                                    const float* __restrict__ We,
                                                    const float* __restrict__ be,
                                                    const float* __restrict__ xp,
                                                    float* __restrict__ out) {
    __shared__ float sW[HEADS * EDIM];
    __shared__ float sb[HEADS];
    if (threadIdx.x < HEADS * EDIM) sW[threadIdx.x] = We[threadIdx.x];
    if (threadIdx.x < HEADS) sb[threadIdx.x] = be[threadIdx.x];
    __syncthreads();

    const int t = blockIdx.x * 256 + threadIdx.x;
    const int e = t >> 5;         // edge id (8 edges per block)
    const int l = t & 31;         // lane within edge
    if (e >= EDGES) return;

    const int src = ei[e];
    const int tgt = ei[EDGES + e];
    const int h = l >> 2;

    // gate for this lane's head
    float4 ea0 = *reinterpret_cast<const float4*>(ea + (size_t)e * EDIM);
    float4 ea1 = *reinterpret_cast<const float4*>(ea + (size_t)e * EDIM + 4);
    float4 wa = *reinterpret_cast<const float4*>(&sW[h * EDIM]);
    float4 wb = *reinterpret_cast<const float4*>(&sW[h * EDIM + 4]);
    float z = sb[h]
            + ea0.x * wa.x + ea0.y * wa.y + ea0.z * wa.z + ea0.w * wa.w
            + ea1.x * wb.x + ea1.y * wb.y + ea1.z * wb.z + ea1.w * wb.w;
    float g = 1.0f / (1.0f + __expf(-z));

    // gather source row quad, gate, scatter-add to target
    float4 v = *reinterpret_cast<const float4*>(xp + (size_t)src * DIM + l * 4);
    float* op = out + (size_t)tgt * DIM + l * 4;
    unsafeAtomicAdd(op + 0, v.x * g);
    unsafeAtomicAdd(op + 1, v.y * g);
    unsafeAtomicAdd(op + 2, v.z * g);
    unsafeAtomicAdd(op + 3, v.w * g);
}

// ---------------------------------------------------------------------------
extern "C" void kernel_launch(void* const* d_in, const int* in_sizes, int n_in,
                              void* d_out, int out_size, void* d_ws, size_t ws_size,
                              hipStream_t stream) {
    const float* x   = (const float*)d_in[0];
    const int*   ei  = (const int*)d_in[1];
    const float* eat = (const float*)d_in[2];
    const float* Wn  = (const float*)d_in[3];
    const float* bn  = (const float*)d_in[4];
    const float* We  = (const float*)d_in[5];
    const float* be  = (const float*)d_in[6];
    float* out = (float*)d_out;

    // workspace layout: [Wt: 128*128 f32][x_proj: NODES*128 f32]
    float* Wt = (float*)d_ws;
    float* xp = Wt + DIM * DIM;

    // out accumulates via atomics -> must zero every call
    hipMemsetAsync(d_out, 0, (size_t)out_size * sizeof(float), stream);

    transpose_w<<<64, 256, 0, stream>>>(Wn, Wt);
    node_proj<<<NODES / 32, 256, 0, stream>>>(x, Wt, bn, xp);
    edge_scatter<<<(EDGES * 32) / 256, 256, 0, stream>>>(ei, eat, We, be, xp, out);
}

// Round 2
// 252.652 us; speedup vs baseline: 5.6052x; 5.6052x over previous
//
#include <hip/hip_runtime.h>

// Problem constants (match reference)
constexpr int NODES = 100000;
constexpr int EDGES = 800000;
constexpr int DIM = 128;       // node dim
constexpr int EDIM = 8;        // edge attr dim
constexpr int HEADS = 8;

// counting-sort scan geometry
constexpr int SCAN_BLK = 512;                 // elements per scan block
constexpr int NSCAN_BLKS = (NODES + SCAN_BLK - 1) / SCAN_BLK;  // 196
constexpr int NPAD = NSCAN_BLKS * SCAN_BLK;   // 100352

// ---------------------------------------------------------------------------
// Kernel A0: transpose W_node (128x128) into workspace: Wt[k][d] = W[d][k]
// ---------------------------------------------------------------------------
__global__ __launch_bounds__(256) void transpose_w(const float* __restrict__ W,
                                                   float* __restrict__ Wt) {
    int idx = blockIdx.x * 256 + threadIdx.x;
    int d = idx & 127;
    int k = idx >> 7;
    Wt[k * DIM + d] = W[d * DIM + k];
}

__device__ inline void fma4(float4& a, float s, const float4& w) {
    a.x += s * w.x; a.y += s * w.y; a.z += s * w.z; a.w += s * w.w;
}

// ---------------------------------------------------------------------------
// Kernel A: x_proj = x @ W.T + b (reads pre-transposed Wt)
// ---------------------------------------------------------------------------
__global__ __launch_bounds__(256) void node_proj(const float* __restrict__ x,
                                                 const float* __restrict__ Wt,
                                                 const float* __restrict__ bn,
                                                 float* __restrict__ xp) {
    __shared__ float sWt[64 * DIM];   // 32KB: half of Wt (64 k-rows)
    __shared__ float sx[32 * DIM];    // 16KB: 32 node rows

    const int tid = threadIdx.x;
    const int row0 = blockIdx.x * 32;

    {
        const float4* x4 = reinterpret_cast<const float4*>(x + (size_t)row0 * DIM);
        float4* sx4 = reinterpret_cast<float4*>(sx);
        #pragma unroll
        for (int i = tid; i < 32 * 32; i += 256) sx4[i] = x4[i];
    }

    const int hw = tid >> 5;
    const int dq = tid & 31;
    const int r0 = hw * 4;

    float4 a0 = {0,0,0,0}, a1 = {0,0,0,0}, a2 = {0,0,0,0}, a3 = {0,0,0,0};

    const float4* Wt4 = reinterpret_cast<const float4*>(Wt);
    float4* sWt4 = reinterpret_cast<float4*>(sWt);

    #pragma unroll
    for (int half = 0; half < 2; ++half) {
        __syncthreads();
        #pragma unroll
        for (int i = tid; i < 64 * 32; i += 256) sWt4[i] = Wt4[half * 2048 + i];
        __syncthreads();

        const int kbase = half * 64;
        #pragma unroll 4
        for (int k = 0; k < 64; ++k) {
            float4 w = *reinterpret_cast<const float4*>(&sWt[k * DIM + dq * 4]);
            float x0 = sx[(r0 + 0) * DIM + kbase + k];
            float x1 = sx[(r0 + 1) * DIM + kbase + k];
            float x2 = sx[(r0 + 2) * DIM + kbase + k];
            float x3 = sx[(r0 + 3) * DIM + kbase + k];
            fma4(a0, x0, w);
            fma4(a1, x1, w);
            fma4(a2, x2, w);
            fma4(a3, x3, w);
        }
    }

    float4 b = *reinterpret_cast<const float4*>(bn + dq * 4);
    a0.x += b.x; a0.y += b.y; a0.z += b.z; a0.w += b.w;
    a1.x += b.x; a1.y += b.y; a1.z += b.z; a1.w += b.w;
    a2.x += b.x; a2.y += b.y; a2.z += b.z; a2.w += b.w;
    a3.x += b.x; a3.y += b.y; a3.z += b.z; a3.w += b.w;

    float4* out4 = reinterpret_cast<float4*>(xp);
    out4[(size_t)(row0 + r0 + 0) * 32 + dq] = a0;
    out4[(size_t)(row0 + r0 + 1) * 32 + dq] = a1;
    out4[(size_t)(row0 + r0 + 2) * 32 + dq] = a2;
    out4[(size_t)(row0 + r0 + 3) * 32 + dq] = a3;
}

// ---------------------------------------------------------------------------
// Counting sort of edges by target node
// ---------------------------------------------------------------------------
__global__ __launch_bounds__(256) void hist_kernel(const int* __restrict__ ei,
                                                   int* __restrict__ cnt) {
    int e = blockIdx.x * 256 + threadIdx.x;
    if (e < EDGES) atomicAdd(&cnt[ei[EDGES + e]], 1);
}

// per-block sums of SCAN_BLK counts
__global__ __launch_bounds__(256) void scan_block_sums(const int* __restrict__ cnt,
                                                       int* __restrict__ partial) {
    __shared__ int sd[256];
    int b = blockIdx.x, t = threadIdx.x;
    int s = cnt[b * SCAN_BLK + t] + cnt[b * SCAN_BLK + 256 + t];
    sd[t] = s; __syncthreads();
    for (int d = 128; d > 0; d >>= 1) {
        if (t < d) sd[t] += sd[t + d];
        __syncthreads();
    }
    if (t == 0) partial[b] = sd[0];
}

// exclusive scan of the (<=256) block partials, in place
__global__ __launch_bounds__(256) void scan_partials(int* __restrict__ partial) {
    __shared__ int sd[256];
    int t = threadIdx.x;
    int v = (t < NSCAN_BLKS) ? partial[t] : 0;
    sd[t] = v; __syncthreads();
    for (int d = 1; d < 256; d <<= 1) {
        int u = (t >= d) ? sd[t - d] : 0;
        __syncthreads();
        sd[t] += u;
        __syncthreads();
    }
    if (t < NSCAN_BLKS) partial[t] = sd[t] - v;   // exclusive
}

// per-block exclusive scan + global offset -> start[]
__global__ __launch_bounds__(256) void scan_write(const int* __restrict__ cnt,
                                                  const int* __restrict__ partial,
                                                  int* __restrict__ start) {
    __shared__ int sd[256];
    int b = blockIdx.x, t = threadIdx.x;
    int i0 = b * SCAN_BLK + 2 * t;
    int c0 = cnt[i0], c1 = cnt[i0 + 1];
    int s = c0 + c1;
    sd[t] = s; __syncthreads();
    for (int d = 1; d < 256; d <<= 1) {
        int u = (t >= d) ? sd[t - d] : 0;
        __syncthreads();
        sd[t] += u;
        __syncthreads();
    }
    int excl = sd[t] - s + partial[b];
    start[i0] = excl;
    start[i0 + 1] = excl + c0;
}

// scatter edge ids into target-sorted order; mutates start so that
// afterwards start[n] == original start[n+1] (segment end for node n)
__global__ __launch_bounds__(256) void scatter_ids(const int* __restrict__ ei,
                                                   int* __restrict__ start,
                                                   int* __restrict__ sortedE) {
    int e = blockIdx.x * 256 + threadIdx.x;
    if (e < EDGES) {
        int p = atomicAdd(&start[ei[EDGES + e]], 1);
        sortedE[p] = e;
    }
}

// ---------------------------------------------------------------------------
// Aggregate: one 32-lane group per target node; lane owns float4 slice.
// begin(n) = (n==0) ? 0 : startM[n-1]; end(n) = startM[n]  (mutated start)
// ---------------------------------------------------------------------------
__global__ __launch_bounds__(256) void aggregate(const int* __restrict__ ei,
                                                 const float* __restrict__ ea,
                                                 const float* __restrict__ We,
                                                 const float* __restrict__ be,
                                                 const float* __restrict__ xp,
                                                 const int* __restrict__ startM,
                                                 const int* __restrict__ sortedE,
                                                 float* __restrict__ out) {
    __shared__ float sW[HEADS * EDIM];
    __shared__ float sb[HEADS];
    if (threadIdx.x < HEADS * EDIM) sW[threadIdx.x] = We[threadIdx.x];
    if (threadIdx.x < HEADS) sb[threadIdx.x] = be[threadIdx.x];
    __syncthreads();

    const int n = blockIdx.x * 8 + (threadIdx.x >> 5);
    if (n >= NODES) return;
    const int l = threadIdx.x & 31;
    const int h = l >> 2;

    const float4 wa = *reinterpret_cast<const float4*>(&sW[h * EDIM]);
    const float4 wb = *reinterpret_cast<const float4*>(&sW[h * EDIM + 4]);
    const float bz = sb[h];

    int j = (n == 0) ? 0 : startM[n - 1];
    const int jend = startM[n];

    float4 acc = {0, 0, 0, 0};

    // 2-way unrolled over the edge segment for gather ILP
    for (; j + 1 < jend; j += 2) {
        int e0 = sortedE[j], e1 = sortedE[j + 1];
        int s0 = ei[e0], s1 = ei[e1];
        float4 p0 = *reinterpret_cast<const float4*>(ea + (size_t)e0 * EDIM);
        float4 q0 = *reinterpret_cast<const float4*>(ea + (size_t)e0 * EDIM + 4);
        float4 p1 = *reinterpret_cast<const float4*>(ea + (size_t)e1 * EDIM);
        float4 q1 = *reinterpret_cast<const float4*>(ea + (size_t)e1 * EDIM + 4);
        float4 v0 = *reinterpret_cast<const float4*>(xp + (size_t)s0 * DIM + l * 4);
        float4 v1 = *reinterpret_cast<const float4*>(xp + (size_t)s1 * DIM + l * 4);
        float z0 = bz + p0.x * wa.x + p0.y * wa.y + p0.z * wa.z + p0.w * wa.w
                      + q0.x * wb.x + q0.y * wb.y + q0.z * wb.z + q0.w * wb.w;
        float z1 = bz + p1.x * wa.x + p1.y * wa.y + p1.z * wa.z + p1.w * wa.w
                      + q1.x * wb.x + q1.y * wb.y + q1.z * wb.z + q1.w * wb.w;
        float g0 = 1.0f / (1.0f + __expf(-z0));
        float g1 = 1.0f / (1.0f + __expf(-z1));
        fma4(acc, g0, v0);
        fma4(acc, g1, v1);
    }
    if (j < jend) {
        int e0 = sortedE[j];
        int s0 = ei[e0];
        float4 p0 = *reinterpret_cast<const float4*>(ea + (size_t)e0 * EDIM);
        float4 q0 = *reinterpret_cast<const float4*>(ea + (size_t)e0 * EDIM + 4);
        float4 v0 = *reinterpret_cast<const float4*>(xp + (size_t)s0 * DIM + l * 4);
        float z0 = bz + p0.x * wa.x + p0.y * wa.y + p0.z * wa.z + p0.w * wa.w
                      + q0.x * wb.x + q0.y * wb.y + q0.z * wb.z + q0.w * wb.w;
        float g0 = 1.0f / (1.0f + __expf(-z0));
        fma4(acc, g0, v0);
    }

    *reinterpret_cast<float4*>(out + (size_t)n * DIM + l * 4) = acc;
}

// ---------------------------------------------------------------------------
// Fallback (R0 path): per-edge atomic scatter, used if ws too small
// ---------------------------------------------------------------------------
__global__ __launch_bounds__(256) void edge_scatter(const int* __restrict__ ei,
                                                    const float* __restrict__ ea,
                                                    const float* __restrict__ We,
                                                    const float* __restrict__ be,
                                                    const float* __restrict__ xp,
                                                    float* __restrict__ out) {
    __shared__ float sW[HEADS * EDIM];
    __shared__ float sb[HEADS];
    if (threadIdx.x < HEADS * EDIM) sW[threadIdx.x] = We[threadIdx.x];
    if (threadIdx.x < HEADS) sb[threadIdx.x] = be[threadIdx.x];
    __syncthreads();

    const int t = blockIdx.x * 256 + threadIdx.x;
    const int e = t >> 5;
    const int l = t & 31;
    if (e >= EDGES) return;

    const int src = ei[e];
    const int tgt = ei[EDGES + e];
    const int h = l >> 2;

    float4 ea0 = *reinterpret_cast<const float4*>(ea + (size_t)e * EDIM);
    float4 ea1 = *reinterpret_cast<const float4*>(ea + (size_t)e * EDIM + 4);
    float4 wa = *reinterpret_cast<const float4*>(&sW[h * EDIM]);
    float4 wb = *reinterpret_cast<const float4*>(&sW[h * EDIM + 4]);
    float z = sb[h]
            + ea0.x * wa.x + ea0.y * wa.y + ea0.z * wa.z + ea0.w * wa.w
            + ea1.x * wb.x + ea1.y * wb.y + ea1.z * wb.z + ea1.w * wb.w;
    float g = 1.0f / (1.0f + __expf(-z));

    float4 v = *reinterpret_cast<const float4*>(xp + (size_t)src * DIM + l * 4);
    float* op = out + (size_t)tgt * DIM + l * 4;
    unsafeAtomicAdd(op + 0, v.x * g);
    unsafeAtomicAdd(op + 1, v.y * g);
    unsafeAtomicAdd(op + 2, v.z * g);
    unsafeAtomicAdd(op + 3, v.w * g);
}

// ---------------------------------------------------------------------------
extern "C" void kernel_launch(void* const* d_in, const int* in_sizes, int n_in,
                              void* d_out, int out_size, void* d_ws, size_t ws_size,
                              hipStream_t stream) {
    const float* x   = (const float*)d_in[0];
    const int*   ei  = (const int*)d_in[1];
    const float* eat = (const float*)d_in[2];
    const float* Wn  = (const float*)d_in[3];
    const float* bn  = (const float*)d_in[4];
    const float* We  = (const float*)d_in[5];
    const float* be  = (const float*)d_in[6];
    float* out = (float*)d_out;

    // workspace layout
    float* Wt = (float*)d_ws;                               // 16384 f32
    float* xp = Wt + DIM * DIM;                             // NODES*128 f32
    int* cnt     = (int*)(xp + (size_t)NODES * DIM);        // NPAD i32
    int* start   = cnt + NPAD;                              // NPAD i32
    int* partial = start + NPAD;                            // 256 i32
    int* sortedE = partial + 256;                           // EDGES i32

    const size_t need = (size_t)(DIM * DIM + NODES * DIM) * 4
                      + (size_t)(2 * NPAD + 256 + EDGES) * 4;

    transpose_w<<<64, 256, 0, stream>>>(Wn, Wt);
    node_proj<<<NODES / 32, 256, 0, stream>>>(x, Wt, bn, xp);

    if (ws_size >= need) {
        // counting-sort by target, then atomic-free segment aggregation
        hipMemsetAsync(cnt, 0, (size_t)NPAD * sizeof(int), stream);
        hist_kernel<<<(EDGES + 255) / 256, 256, 0, stream>>>(ei, cnt);
        scan_block_sums<<<NSCAN_BLKS, 256, 0, stream>>>(cnt, partial);
        scan_partials<<<1, 256, 0, stream>>>(partial);
        scan_write<<<NSCAN_BLKS, 256, 0, stream>>>(cnt, partial, start);
        scatter_ids<<<(EDGES + 255) / 256, 256, 0, stream>>>(ei, start, sortedE);
        aggregate<<<(NODES + 7) / 8, 256, 0, stream>>>(ei, eat, We, be, xp,
                                                       start, sortedE, out);
    } else {
        // fallback: R0 atomic path
        hipMemsetAsync(d_out, 0, (size_t)out_size * sizeof(float), stream);
        edge_scatter<<<(EDGES * 32) / 256, 256, 0, stream>>>(ei, eat, We, be, xp, out);
    }
}